// Round 4
// baseline (2907.530 us; speedup 1.0000x reference)
//
#include <hip/hip_runtime.h>

#define HW 65536
#define RSTRIDE 68   // floats per private LDS row; 68*4=272 B, 16B-aligned for b128

// ---------------- cc precompute: cc[l*1024 + s*256 + m] = sum_d cb[...][d]^2 ----
// (replicates the 4-partial summation order of the previously-passing kernel)
__global__ void cc_kernel(const float* __restrict__ cbk, float* __restrict__ cc) {
    const int i = blockIdx.x * 256 + threadIdx.x;   // [0, 3*4*256)
    if (i < 3072) {
        const float* p = cbk + (size_t)i * 16;
        float s0 = 0.f, s1 = 0.f, s2 = 0.f, s3 = 0.f;
        #pragma unroll
        for (int d4 = 0; d4 < 4; ++d4) {
            const float4 v = *(const float4*)(p + 4 * d4);
            s0 = fmaf(v.x, v.x, s0); s1 = fmaf(v.y, v.y, s1);
            s2 = fmaf(v.z, v.z, s2); s3 = fmaf(v.w, v.w, s3);
        }
        cc[i] = (s0 + s1) + (s2 + s3);
    }
}

// ---------------- fused kernel: one row per lane, 256 rows per block ------------
// Activations: per-lane private LDS row (distinct-address ds_read_b128, 16/matmul).
// Weights/codebooks: wave-uniform addresses -> compiler emits s_load; they feed
// v_fma as the single legal SGPR operand. No __syncthreads anywhere.
__global__ __launch_bounds__(256, 2)
void hpp_fused(const float* __restrict__ x,
               const float* __restrict__ W_enc, const float* __restrict__ b_enc,
               const float* __restrict__ W_qh,  const float* __restrict__ b_qh,
               const float* __restrict__ W_lh,  const float* __restrict__ b_lh,
               const float* __restrict__ W_dq,  const float* __restrict__ b_dq,
               const float* __restrict__ W_rh,  const float* __restrict__ b_rh,
               const float* __restrict__ cbk,   const float* __restrict__ ccws,
               float* __restrict__ out, float* __restrict__ loss_out)
{
    __shared__ __align__(16) float lds[256 * RSTRIDE];   // 69632 B -> 2 blocks/CU

    const int t    = threadIdx.x;
    const int lane = t & 63;
    const int row  = blockIdx.x * 256 + t;        // this lane's row index n
    const int b    = row >> 16;                   // HW = 65536 rows per image
    const int hw   = row & (HW - 1);
    const size_t iobase = (size_t)b * (64 * HW) + hw;   // + c*HW per channel

    float* __restrict__ my = lds + t * RSTRIDE;   // private activation row

    // ---- stage x: my[c] = x[b, c, hw]  (each global load coalesced across lanes)
    for (int c4 = 0; c4 < 16; ++c4) {
        float4 v;
        v.x = x[iobase + (size_t)(4 * c4 + 0) * HW];
        v.y = x[iobase + (size_t)(4 * c4 + 1) * HW];
        v.z = x[iobase + (size_t)(4 * c4 + 2) * HW];
        v.w = x[iobase + (size_t)(4 * c4 + 3) * HW];
        *(float4*)(my + 4 * c4) = v;
    }

    float acc[64];        // matmul output / q / quant
    float zl[64];         // z @ W_lh + b_lh  (pre-computed next-residual term)
    float restored[64];
    #pragma unroll
    for (int c = 0; c < 64; ++c) restored[c] = 0.f;
    float loss_acc = 0.f;

    // mm: acc[c] = sum_k my[k] * W[k][c]  (+ bias added at the end, k ascending)
    auto mm = [&](const float* __restrict__ Wl, const float* __restrict__ bl,
                  float* __restrict__ accp) {
        #pragma unroll
        for (int c = 0; c < 64; ++c) accp[c] = 0.f;
        for (int k4 = 0; k4 < 16; ++k4) {              // dynamic loop: small code
            const float4 a = *(const float4*)(my + 4 * k4);   // 1 LDS instr / 256 FMA
            const float* __restrict__ wr = Wl + (4 * k4) * 64; // uniform -> s_load
            #pragma unroll
            for (int c = 0; c < 64; ++c) accp[c] = fmaf(a.x, wr[c],       accp[c]);
            #pragma unroll
            for (int c = 0; c < 64; ++c) accp[c] = fmaf(a.y, wr[64 + c],  accp[c]);
            #pragma unroll
            for (int c = 0; c < 64; ++c) accp[c] = fmaf(a.z, wr[128 + c], accp[c]);
            #pragma unroll
            for (int c = 0; c < 64; ++c) accp[c] = fmaf(a.w, wr[192 + c], accp[c]);
        }
        #pragma unroll
        for (int c = 0; c < 64; ++c) accp[c] += bl[c];
    };
    auto store_acc = [&](const float* __restrict__ ap) {
        #pragma unroll
        for (int i = 0; i < 16; ++i)
            *(float4*)(my + 4 * i) = *(const float4*)(ap + 4 * i);
    };

    for (int L = 0; L < 3; ++L) {
        const int  Lo  = L * 4096;
        const int  Lb  = L * 64;

        // z = residual @ W_enc + b_enc           (my = residual -> my = z)
        mm(W_enc + Lo, b_enc + Lb, acc);
        store_acc(acc);
        // zl = z @ W_lh + b_lh  (early, so z's LDS slot can be recycled)
        if (L < 2) mm(W_lh + Lo, b_lh + Lb, zl);
        // q = z @ W_qh + b_qh                    (-> acc, stays in registers)
        mm(W_qh + Lo, b_qh + Lb, acc);

        // ---- VQ scan: fully per-lane; cb/cc stream via scalar pipe ----
        const float* __restrict__ cbL = cbk  + (size_t)L * 4 * 4096;
        const float* __restrict__ ccL = ccws + L * 1024;
        #pragma unroll
        for (int s = 0; s < 4; ++s) {
            const float* __restrict__ cbs = cbL + s * 4096;   // uniform
            const float* __restrict__ ccs = ccL + s * 256;    // uniform
            float qq = 0.f;
            #pragma unroll
            for (int d = 0; d < 16; ++d) qq = fmaf(acc[s * 16 + d], acc[s * 16 + d], qq);
            float best = 3.4e38f; int bi = 0;
            #pragma unroll 4
            for (int m = 0; m < 256; ++m) {
                const float* __restrict__ cp = cbs + m * 16;  // uniform -> s_load_dwordx16
                float d0 = 0.f, d1 = 0.f, d2 = 0.f, d3 = 0.f;
                #pragma unroll
                for (int d4 = 0; d4 < 4; ++d4) {              // 4-partial order == previous passing kernel
                    d0 = fmaf(acc[s * 16 + 4 * d4 + 0], cp[4 * d4 + 0], d0);
                    d1 = fmaf(acc[s * 16 + 4 * d4 + 1], cp[4 * d4 + 1], d1);
                    d2 = fmaf(acc[s * 16 + 4 * d4 + 2], cp[4 * d4 + 2], d2);
                    d3 = fmaf(acc[s * 16 + 4 * d4 + 3], cp[4 * d4 + 3], d3);
                }
                const float dot  = (d0 + d1) + (d2 + d3);
                const float dist = qq - 2.0f * dot + ccs[m];  // same expr as passing kernel
                if (dist < best) { best = dist; bi = m; }     // strict < : first-min (jnp argmin)
            }
            // gather hard = cb[bi] (divergent, L1-resident), loss, quantize in regs
            const float* __restrict__ hp = cbs + bi * 16;     // divergent -> VMEM gather
            #pragma unroll
            for (int d4 = 0; d4 < 4; ++d4) {
                const float4 h = *(const float4*)(hp + 4 * d4);
                float e;
                e = acc[s*16+4*d4+0] - h.x; loss_acc = fmaf(e, e, loss_acc); acc[s*16+4*d4+0] = h.x;
                e = acc[s*16+4*d4+1] - h.y; loss_acc = fmaf(e, e, loss_acc); acc[s*16+4*d4+1] = h.y;
                e = acc[s*16+4*d4+2] - h.z; loss_acc = fmaf(e, e, loss_acc); acc[s*16+4*d4+2] = h.z;
                e = acc[s*16+4*d4+3] - h.w; loss_acc = fmaf(e, e, loss_acc); acc[s*16+4*d4+3] = h.w;
            }
        }

        // deq = quant @ W_dq + b_dq
        store_acc(acc);                        // my = quant
        mm(W_dq + Lo, b_dq + Lb, acc);         // acc = deq
        if (L < 2) {
            #pragma unroll
            for (int c = 0; c < 64; ++c) zl[c] -= acc[c];     // zl = next residual
        }
        store_acc(acc);                        // my = deq
        mm(W_rh + Lo, b_rh + Lb, acc);         // acc = deq @ W_rh + b_rh
        #pragma unroll
        for (int c = 0; c < 64; ++c) restored[c] += acc[c];
        if (L < 2) store_acc(zl);              // my = residual for next layer
    }

    // ---- output: coalesced per-channel stores ----
    #pragma unroll
    for (int c = 0; c < 64; ++c)
        out[iobase + (size_t)c * HW] = restored[c];

    // ---- loss: per-wave shuffle reduce -> one atomic per wave ----
    #pragma unroll
    for (int off = 32; off > 0; off >>= 1) loss_acc += __shfl_down(loss_acc, off, 64);
    if (lane == 0)
        atomicAdd(loss_out, loss_acc * (1.25f / 16777216.0f));
}

extern "C" void kernel_launch(void* const* d_in, const int* in_sizes, int n_in,
                              void* d_out, int out_size, void* d_ws, size_t ws_size,
                              hipStream_t stream) {
    const float* x     = (const float*)d_in[0];
    const float* W_enc = (const float*)d_in[1];
    const float* b_enc = (const float*)d_in[2];
    const float* W_qh  = (const float*)d_in[3];
    const float* b_qh  = (const float*)d_in[4];
    const float* W_lh  = (const float*)d_in[5];
    const float* b_lh  = (const float*)d_in[6];
    const float* W_dq  = (const float*)d_in[7];
    const float* b_dq  = (const float*)d_in[8];
    const float* W_rh  = (const float*)d_in[9];
    const float* b_rh  = (const float*)d_in[10];
    const float* cbk   = (const float*)d_in[11];

    float* out      = (float*)d_out;
    float* loss_out = out + (out_size - 1);   // outputs concatenated: [B*C*H*W][loss]
    float* ccws     = (float*)d_ws;           // 3072 floats of workspace

    hipMemsetAsync(loss_out, 0, sizeof(float), stream);   // d_out is poisoned each launch
    cc_kernel<<<dim3(12), dim3(256), 0, stream>>>(cbk, ccws);
    hpp_fused<<<dim3(1024), dim3(256), 0, stream>>>(
        x, W_enc, b_enc, W_qh, b_qh, W_lh, b_lh, W_dq, b_dq, W_rh, b_rh,
        cbk, ccws, out, loss_out);
}